// Round 2
// baseline (459.401 us; speedup 1.0000x reference)
//
#include <hip/hip_runtime.h>
#include <hip/hip_cooperative_groups.h>

namespace cg = cooperative_groups;

// Problem constants (from reference)
#define TT 128    // time points
#define DD 64     // state dim
#define HH 256    // f-net hidden
#define HKD 128   // kernel-net hidden
#define HD (HKD*DD)        // 8192
#define NCHUNK 64          // jh chunks of 256 (= 2 j's each)
#define NBLK 256           // cooperative grid: 1 block per CU (co-residency guaranteed)

// Shared memory union — max member (g1) = 16 KB.
union __attribute__((aligned(16))) SharedU {
    struct { float red[4][64]; float ys[DD]; float hs[HH]; float fs[DD]; } f;   // MLP phases
    struct { float Bpart[2][HKD]; float Bs[HKD]; float red[4][64]; } g0;        // it0 G
    struct { float Fs[8][DD]; } m;                                              // M phase
    struct { float As[8 * 256]; float red[4][8][64]; } g1;                      // G1 phase
};

// f-MLP: requires sm.f.ys valid (+synced); leaves f(y) in sm.f.fs (synced).
__device__ __forceinline__ void mlp_f(SharedU& sm, int tid,
                                      const float* __restrict__ W1, const float* __restrict__ b1,
                                      const float* __restrict__ W2, const float* __restrict__ b2) {
    int part = tid >> 6, d = tid & 63;
    float acc = b1[tid];
    #pragma unroll 8
    for (int e = 0; e < DD; ++e) acc += sm.f.ys[e] * W1[e * HH + tid];
    sm.f.hs[tid] = tanhf(acc);
    __syncthreads();
    float s = 0.f;
    #pragma unroll 8
    for (int h = part * 64; h < part * 64 + 64; ++h) s += sm.f.hs[h] * W2[h * DD + d];
    sm.f.red[part][d] = s;
    __syncthreads();
    if (part == 0)
        sm.f.fs[d] = b2[d] + sm.f.red[0][d] + sm.f.red[1][d] + sm.f.red[2][d] + sm.f.red[3][d];
    __syncthreads();
}

// bF[d] = sum_e bk2[d*DD+e]*fs[e]; valid for all threads on return.
__device__ __forceinline__ float bk2dot(SharedU& sm, int tid, const float* __restrict__ bk2) {
    int part = tid >> 6, d = tid & 63;
    float s = 0.f;
    #pragma unroll
    for (int e = part * 16; e < part * 16 + 16; ++e) s += bk2[d * DD + e] * sm.f.fs[e];
    sm.f.red[part][d] = s;
    __syncthreads();
    return sm.f.red[0][d] + sm.f.red[1][d] + sm.f.red[2][d] + sm.f.red[3][d];
}

extern "C" __global__ void __launch_bounds__(256, 2)
mega(const float* __restrict__ z0, const float* __restrict__ t,
     const float* __restrict__ W1, const float* __restrict__ b1,
     const float* __restrict__ W2, const float* __restrict__ b2,
     const float* __restrict__ Wk1, const float* __restrict__ bk1,
     const float* __restrict__ Wk2, const float* __restrict__ bk2,
     float* __restrict__ A, float* __restrict__ M,
     float* __restrict__ F, float* __restrict__ bF,
     float* __restrict__ G, float* __restrict__ P,
     float* __restrict__ M0, float* __restrict__ bF0,
     float* __restrict__ out)
{
    cg::grid_group grid = cg::this_grid();
    const int b = blockIdx.x, tid = threadIdx.x;
    const int part = tid >> 6, d = tid & 63;
    __shared__ SharedU sm;
    const float dt = t[1] - t[0];

    // ===== P0: precompute A[i][j][h] = w_ij * tanh(t_i*wk0 + t_j*wk1 + bk)  =====
    // (iteration-invariant; removes all tanh from the serial chain)
    // blocks 0..31 additionally: f0 = f(z0) -> M0 slice; block 0 -> bF0.
    if (b < 32) {
        if (tid < DD) sm.f.ys[tid] = z0[tid];
        __syncthreads();
        mlp_f(sm, tid, W1, b1, W2, b2);
        if (b == 0) {
            float v = bk2dot(sm, tid, bk2);
            if (part == 0) bF0[d] = v;
        }
        int hd = b * 256 + tid;
        const float* Wrow = Wk2 + (size_t)(hd >> 6) * (DD * DD) + (size_t)(hd & 63) * DD;
        float a = 0.f;
        #pragma unroll
        for (int e = 0; e < DD; e += 8) {
            float4 wa = *(const float4*)(Wrow + e);
            float4 wb = *(const float4*)(Wrow + e + 4);
            float4 fa = *(const float4*)&sm.f.fs[e];
            float4 fb = *(const float4*)&sm.f.fs[e + 4];
            a += fa.x*wa.x + fa.y*wa.y + fa.z*wa.z + fa.w*wa.w
               + fb.x*wb.x + fb.y*wb.y + fb.z*wb.z + fb.w*wb.w;
        }
        M0[hd] = a;
    }
    {
        const int h = tid & 127;                        // constant across k
        const float wk0 = Wk1[h], wk1v = Wk1[HKD + h], bk = bk1[h];
        const int base = b * (TT * TT * HKD / NBLK);    // 8192 entries/block
        #pragma unroll 4
        for (int k = 0; k < TT * TT * HKD / NBLK / 256; ++k) {   // 32 per thread
            int n = base + k * 256 + tid;
            int i = n >> 14, j = (n >> 7) & 127;
            float w = (i == 0 || j > i) ? 0.f : dt * ((j == 0 || j == i) ? 0.5f : 1.f);
            float v = 0.f;
            if (w != 0.f)   // wave-uniform branch (i,j uniform within a wave)
                v = w * tanhf(t[i] * wk0 + t[j] * wk1v + bk);
            A[n] = v;
        }
    }
    grid.sync();

    // ===== P1 (it0): G_i = sum_h B[i,h]*M0[h,d] + dt*i*bF0[d],  B = rowsum of A =====
    if (b < TT) {
        const int i = b;
        const int h = tid & 127, half = tid >> 7;
        float bsum = 0.f;
        const float* Ai = A + (size_t)i * (TT * HKD);
        for (int j = half; j <= i; j += 2) bsum += Ai[j * HKD + h];
        sm.g0.Bpart[half][h] = bsum;
        __syncthreads();
        if (tid < HKD) sm.g0.Bs[tid] = sm.g0.Bpart[0][tid] + sm.g0.Bpart[1][tid];
        __syncthreads();
        float a = 0.f;
        #pragma unroll 8
        for (int h2 = part * 32; h2 < part * 32 + 32; ++h2) a += sm.g0.Bs[h2] * M0[h2 * DD + d];
        sm.g0.red[part][d] = a;
        __syncthreads();
        if (part == 0) {
            float g = sm.g0.red[0][d] + sm.g0.red[1][d] + sm.g0.red[2][d] + sm.g0.red[3][d];
            if (i > 0) g += dt * (float)i * bF0[d];
            G[i * DD + d] = g;
        }
    }
    grid.sync();

    // ===== it = 1, 2 =====
    for (int it = 1; it < 3; ++it) {
        const int fin = (it == 2);

        // --- F phase: blocks 0..127: y_j from prefix of G, then F[j], bF[j] ---
        if (b < TT) {
            const int j = b;
            float s = 0.f;
            if (j > 0) {
                for (int jp = part; jp <= j; jp += 4) {
                    float w = (jp == 0 || jp == j) ? 0.5f : 1.0f;
                    s += w * G[jp * DD + d];
                }
            }
            sm.f.red[part][d] = s;
            __syncthreads();
            if (part == 0)
                sm.f.ys[d] = z0[d] + dt * (sm.f.red[0][d] + sm.f.red[1][d] + sm.f.red[2][d] + sm.f.red[3][d]);
            __syncthreads();
            mlp_f(sm, tid, W1, b1, W2, b2);
            if (part == 0) F[j * DD + d] = sm.f.fs[d];
            float v = bk2dot(sm, tid, bk2);
            if (part == 0) bF[j * DD + d] = v;
        }
        grid.sync();

        // --- M phase: 512 units over 256 blocks (2 each). M[j,hd] = sum_e F[j,e]*Wk2 ---
        for (int u = b; u < 512; u += NBLK) {
            const int hd = (u & 31) * 256 + tid;
            const int j0 = (u >> 5) * 8;
            __syncthreads();   // protect Fs reuse across units
            for (int k2 = tid; k2 < 8 * DD; k2 += 256) sm.m.Fs[k2 >> 6][k2 & 63] = F[j0 * DD + k2];
            __syncthreads();
            float acc[8] = {0.f,0.f,0.f,0.f,0.f,0.f,0.f,0.f};
            const float* Wrow = Wk2 + (size_t)(hd >> 6) * (DD * DD) + (size_t)(hd & 63) * DD;
            for (int e = 0; e < DD; e += 8) {
                float4 wa = *(const float4*)(Wrow + e);
                float4 wb = *(const float4*)(Wrow + e + 4);
                #pragma unroll
                for (int r = 0; r < 8; ++r) {
                    float4 f0 = *(const float4*)&sm.m.Fs[r][e];
                    float4 f1 = *(const float4*)&sm.m.Fs[r][e + 4];
                    acc[r] += f0.x*wa.x + f0.y*wa.y + f0.z*wa.z + f0.w*wa.w
                            + f1.x*wb.x + f1.y*wb.y + f1.z*wb.z + f1.w*wb.w;
                }
            }
            #pragma unroll
            for (int r = 0; r < 8; ++r) M[(size_t)(j0 + r) * HD + hd] = acc[r];
        }
        grid.sync();

        // --- G1 phase: 544 active (itile,c) units over 256 blocks (2-3 each) ---
        if (fin && b == 0 && tid < DD) out[tid] = z0[tid];   // seed out = z0
        for (int u = b; u < 544; u += NBLK) {
            int uu = u, itile = 0;
            while (uu >= 4 * (itile + 1)) { uu -= 4 * (itile + 1); ++itile; }
            const int c = uu;               // c <= 4*itile+3 by construction
            __syncthreads();                // protect As/red reuse across units
            const float* Asrc = A + ((size_t)(itile * 8) * TT + 2 * c) * HKD;
            for (int q = tid; q < 8 * 64; q += 256) {       // 8 rows x 256 floats, float4
                int r = q >> 6, c4 = q & 63;
                ((float4*)sm.g1.As)[r * 64 + c4] =
                    *(const float4*)(Asrc + (size_t)r * TT * HKD + c4 * 4);
            }
            __syncthreads();
            float acc[8] = {0.f,0.f,0.f,0.f,0.f,0.f,0.f,0.f};
            const float* Mp = M + ((size_t)c * 256) * DD + d;
            const int jl0 = part * 64;
            for (int jl = jl0; jl < jl0 + 64; jl += 8) {
                float m0 = Mp[(size_t)(jl + 0) * DD];
                float m1 = Mp[(size_t)(jl + 1) * DD];
                float m2 = Mp[(size_t)(jl + 2) * DD];
                float m3 = Mp[(size_t)(jl + 3) * DD];
                float m4 = Mp[(size_t)(jl + 4) * DD];
                float m5 = Mp[(size_t)(jl + 5) * DD];
                float m6 = Mp[(size_t)(jl + 6) * DD];
                float m7 = Mp[(size_t)(jl + 7) * DD];
                #pragma unroll
                for (int r = 0; r < 8; ++r) {
                    float4 a0 = *(const float4*)&sm.g1.As[r * 256 + jl];
                    float4 a1 = *(const float4*)&sm.g1.As[r * 256 + jl + 4];
                    acc[r] += a0.x*m0 + a0.y*m1 + a0.z*m2 + a0.w*m3
                            + a1.x*m4 + a1.y*m5 + a1.z*m6 + a1.w*m7;
                }
            }
            #pragma unroll
            for (int r = 0; r < 8; ++r) sm.g1.red[part][r][d] = acc[r];
            __syncthreads();
            if (part == 0) {
                #pragma unroll
                for (int r = 0; r < 8; ++r) {
                    float v = sm.g1.red[0][r][d] + sm.g1.red[1][r][d]
                            + sm.g1.red[2][r][d] + sm.g1.red[3][r][d];
                    P[(size_t)c * (TT * DD) + (itile * 8 + r) * DD + d] = v;
                }
            }
        }
        grid.sync();

        // --- Gfin phase: blocks 0..127: G[j] = sum_c P[c,j,:] + dt*trap(bF) ---
        if (b < TT) {
            const int j = b;
            float a = 0.f;
            const int cmax = j >> 1;
            for (int c = part; c <= cmax; c += 4) a += P[(size_t)c * (TT * DD) + j * DD + d];
            if (j > 0) {
                float s2 = 0.f;
                for (int jp = part; jp <= j; jp += 4) {
                    float w = (jp == 0 || jp == j) ? 0.5f : 1.0f;
                    s2 += w * bF[jp * DD + d];
                }
                a += dt * s2;
            }
            sm.f.red[part][d] = a;
            __syncthreads();
            if (part == 0) {
                float v = sm.f.red[0][d] + sm.f.red[1][d] + sm.f.red[2][d] + sm.f.red[3][d];
                G[j * DD + d] = v;
                if (fin) {
                    float wj = (j == 0 || j == TT - 1) ? 0.5f : 1.0f;
                    atomicAdd(&out[d], dt * wj * v);
                }
            }
        }
        if (it == 1) grid.sync();
    }
}

// ===========================================================================
// Fallback path: the proven r9 10-launch pipeline (used if cooperative launch
// is refused by the runtime). Identical math, measured 185.7 us.
// ===========================================================================
__global__ void __launch_bounds__(256)
k_F0M0(const float* __restrict__ z0,
       const float* __restrict__ W1, const float* __restrict__ b1,
       const float* __restrict__ W2, const float* __restrict__ b2,
       const float* __restrict__ bk2, const float* __restrict__ Wk2,
       float* __restrict__ M0, float* __restrict__ bF0) {
    int bx = blockIdx.x, tid = threadIdx.x;
    int part = tid >> 6, d = tid & 63;
    __shared__ float red[4][64];
    __shared__ float ys[DD];
    __shared__ float hs[HH];
    __shared__ __attribute__((aligned(16))) float fs[DD];
    if (tid < DD) ys[tid] = z0[tid];
    __syncthreads();
    float acc = b1[tid];
    #pragma unroll 8
    for (int e = 0; e < DD; ++e) acc += ys[e] * W1[e * HH + tid];
    hs[tid] = tanhf(acc);
    __syncthreads();
    {
        float s = 0.f;
        #pragma unroll 8
        for (int h = part * 64; h < part * 64 + 64; ++h) s += hs[h] * W2[h * DD + d];
        red[part][d] = s;
    }
    __syncthreads();
    if (part == 0)
        fs[d] = b2[d] + red[0][d] + red[1][d] + red[2][d] + red[3][d];
    __syncthreads();
    if (bx == 0) {
        float s = 0.f;
        #pragma unroll
        for (int e = part * 16; e < part * 16 + 16; ++e) s += bk2[d * DD + e] * fs[e];
        red[part][d] = s;
        __syncthreads();
        if (part == 0)
            bF0[d] = red[0][d] + red[1][d] + red[2][d] + red[3][d];
    }
    int hd = bx * 256 + tid;
    const float* Wrow = Wk2 + (size_t)(hd >> 6) * (DD * DD) + (size_t)(hd & 63) * DD;
    float a = 0.f;
    #pragma unroll
    for (int e = 0; e < DD; e += 8) {
        float4 wa = *(const float4*)(Wrow + e);
        float4 wb = *(const float4*)(Wrow + e + 4);
        float4 fa = *(const float4*)&fs[e];
        float4 fb = *(const float4*)&fs[e + 4];
        a += fa.x*wa.x + fa.y*wa.y + fa.z*wa.z + fa.w*wa.w
           + fb.x*wb.x + fb.y*wb.y + fb.z*wb.z + fb.w*wb.w;
    }
    M0[hd] = a;
}

__global__ void __launch_bounds__(256)
k_G0(const float* __restrict__ t, const float* __restrict__ Wk1,
     const float* __restrict__ bk1, const float* __restrict__ M0,
     const float* __restrict__ bF0, float* __restrict__ G) {
    int i = blockIdx.x, tid = threadIdx.x;
    int part = tid >> 6, d = tid & 63;
    __shared__ float Bpart[2][HKD];
    __shared__ float Bs[HKD];
    __shared__ float red[4][64];
    float dt = t[1] - t[0];
    int h = tid & 127, half = tid >> 7;
    float b = 0.f;
    if (i > 0) {
        float wk0 = Wk1[h], wk1v = Wk1[HKD + h], bk = bk1[h];
        float ti = t[i];
        for (int j = half; j <= i; j += 2) {
            float w = dt * ((j == 0 || j == i) ? 0.5f : 1.0f);
            b += w * tanhf(ti * wk0 + t[j] * wk1v + bk);
        }
    }
    Bpart[half][h] = b;
    __syncthreads();
    if (tid < HKD) Bs[tid] = Bpart[0][tid] + Bpart[1][tid];
    __syncthreads();
    float a = 0.f;
    #pragma unroll 8
    for (int h2 = part * 32; h2 < part * 32 + 32; ++h2)
        a += Bs[h2] * M0[h2 * DD + d];
    red[part][d] = a;
    __syncthreads();
    if (part == 0) {
        float g = red[0][d] + red[1][d] + red[2][d] + red[3][d];
        if (i > 0) g += dt * (float)i * bF0[d];
        G[i * DD + d] = g;
    }
}

__global__ void __launch_bounds__(256)
k_F(const float* __restrict__ G, const float* __restrict__ z0,
    const float* __restrict__ t,
    const float* __restrict__ W1, const float* __restrict__ b1,
    const float* __restrict__ W2, const float* __restrict__ b2,
    const float* __restrict__ bk2,
    float* __restrict__ F, float* __restrict__ bF) {
    int j = blockIdx.x, tid = threadIdx.x;
    int part = tid >> 6, d = tid & 63;
    __shared__ float red[4][64];
    __shared__ float ys[DD];
    __shared__ float hs[HH];
    __shared__ float fs[DD];
    float dt = t[1] - t[0];
    {
        float s = 0.f;
        if (j > 0) {
            for (int jp = part; jp <= j; jp += 4) {
                float w = (jp == 0 || jp == j) ? 0.5f : 1.0f;
                s += w * G[jp * DD + d];
            }
        }
        red[part][d] = s;
        __syncthreads();
        if (part == 0)
            ys[d] = z0[d] + dt * (red[0][d] + red[1][d] + red[2][d] + red[3][d]);
    }
    __syncthreads();
    float acc = b1[tid];
    #pragma unroll 8
    for (int e = 0; e < DD; ++e) acc += ys[e] * W1[e * HH + tid];
    hs[tid] = tanhf(acc);
    __syncthreads();
    {
        float s = 0.f;
        #pragma unroll 8
        for (int h = part * 64; h < part * 64 + 64; ++h) s += hs[h] * W2[h * DD + d];
        red[part][d] = s;
    }
    __syncthreads();
    if (part == 0) {
        float a = b2[d] + red[0][d] + red[1][d] + red[2][d] + red[3][d];
        fs[d] = a;
        F[j * DD + d] = a;
    }
    __syncthreads();
    {
        float s = 0.f;
        #pragma unroll
        for (int e = part * 16; e < part * 16 + 16; ++e) s += bk2[d * DD + e] * fs[e];
        red[part][d] = s;
    }
    __syncthreads();
    if (part == 0)
        bF[j * DD + d] = red[0][d] + red[1][d] + red[2][d] + red[3][d];
}

__global__ void __launch_bounds__(256)
k_M(const float* __restrict__ F, const float* __restrict__ Wk2,
    float* __restrict__ M) {
    int tid = threadIdx.x;
    int hd = blockIdx.x * 256 + tid;
    int j0 = blockIdx.y * 8;
    __shared__ __attribute__((aligned(16))) float Fs[8][64];
    for (int k = tid; k < 8 * DD; k += 256) Fs[k >> 6][k & 63] = F[j0 * DD + k];
    __syncthreads();
    float acc[8] = {0.f,0.f,0.f,0.f,0.f,0.f,0.f,0.f};
    const float* Wrow = Wk2 + (size_t)(hd >> 6) * (DD * DD) + (size_t)(hd & 63) * DD;
    for (int e = 0; e < DD; e += 8) {
        float4 wa = *(const float4*)(Wrow + e);
        float4 wb = *(const float4*)(Wrow + e + 4);
        #pragma unroll
        for (int r = 0; r < 8; ++r) {
            float4 f0 = *(const float4*)&Fs[r][e];
            float4 f1 = *(const float4*)&Fs[r][e + 4];
            acc[r] += f0.x*wa.x + f0.y*wa.y + f0.z*wa.z + f0.w*wa.w
                    + f1.x*wb.x + f1.y*wb.y + f1.z*wb.z + f1.w*wb.w;
        }
    }
    #pragma unroll
    for (int r = 0; r < 8; ++r) M[(size_t)(j0 + r) * HD + hd] = acc[r];
}

__global__ void __launch_bounds__(256)
k_G1(const float* __restrict__ t, const float* __restrict__ Wk1,
     const float* __restrict__ bk1, const float* __restrict__ M,
     float* __restrict__ P, const float* __restrict__ z0,
     float* __restrict__ out, int final_it) {
    int itile = blockIdx.x, c = blockIdx.y;
    if (c > 4 * itile + 3) return;
    __shared__ __attribute__((aligned(16))) float As[8 * 256];
    __shared__ float red[4][8][64];
    int tid = threadIdx.x, sub = tid >> 6, d = tid & 63;
    {
        float dt = t[1] - t[0];
        int h = tid & 127;
        int j = 2 * c + (tid >> 7);
        float wk0 = Wk1[h], wk1v = Wk1[HKD + h], bk = bk1[h];
        float tj = t[j];
        #pragma unroll
        for (int k = 0; k < 8; ++k) {
            int i = itile * 8 + k;
            float w = (i == 0 || j > i) ? 0.f : dt * ((j == 0 || j == i) ? 0.5f : 1.0f);
            As[k * 256 + tid] = w * tanhf(t[i] * wk0 + tj * wk1v + bk);
        }
    }
    if (final_it && itile == 0 && c == 0 && tid < DD) out[tid] = z0[tid];
    __syncthreads();
    float acc[8] = {0.f,0.f,0.f,0.f,0.f,0.f,0.f,0.f};
    const float* Mp = M + ((size_t)c * 256) * DD + d;
    int jl0 = sub * 64;
    for (int jl = jl0; jl < jl0 + 64; jl += 8) {
        float m0 = Mp[(size_t)(jl + 0) * DD];
        float m1 = Mp[(size_t)(jl + 1) * DD];
        float m2 = Mp[(size_t)(jl + 2) * DD];
        float m3 = Mp[(size_t)(jl + 3) * DD];
        float m4 = Mp[(size_t)(jl + 4) * DD];
        float m5 = Mp[(size_t)(jl + 5) * DD];
        float m6 = Mp[(size_t)(jl + 6) * DD];
        float m7 = Mp[(size_t)(jl + 7) * DD];
        #pragma unroll
        for (int r = 0; r < 8; ++r) {
            float4 a0 = *(const float4*)&As[r * 256 + jl];
            float4 a1 = *(const float4*)&As[r * 256 + jl + 4];
            acc[r] += a0.x*m0 + a0.y*m1 + a0.z*m2 + a0.w*m3
                    + a1.x*m4 + a1.y*m5 + a1.z*m6 + a1.w*m7;
        }
    }
    #pragma unroll
    for (int r = 0; r < 8; ++r) red[sub][r][d] = acc[r];
    __syncthreads();
    if (sub == 0) {
        #pragma unroll
        for (int r = 0; r < 8; ++r) {
            float v = red[0][r][d] + red[1][r][d] + red[2][r][d] + red[3][r][d];
            P[(size_t)c * (TT * DD) + (itile * 8 + r) * DD + d] = v;
        }
    }
}

__global__ void __launch_bounds__(256)
k_Gfin(const float* __restrict__ P, const float* __restrict__ bF,
       const float* __restrict__ t, float* __restrict__ G,
       float* __restrict__ out, int final_it) {
    int j = blockIdx.x, tid = threadIdx.x;
    int part = tid >> 6, d = tid & 63;
    __shared__ float red[4][64];
    float dt = t[1] - t[0];
    float a = 0.f;
    int cmax = j >> 1;
    for (int c = part; c <= cmax; c += 4) a += P[(size_t)c * (TT * DD) + j * DD + d];
    if (j > 0) {
        float s = 0.f;
        for (int jp = part; jp <= j; jp += 4) {
            float w = (jp == 0 || jp == j) ? 0.5f : 1.0f;
            s += w * bF[jp * DD + d];
        }
        a += dt * s;
    }
    red[part][d] = a;
    __syncthreads();
    if (part == 0) {
        float v = red[0][d] + red[1][d] + red[2][d] + red[3][d];
        G[j * DD + d] = v;
        if (final_it) {
            float wj = (j == 0 || j == TT - 1) ? 0.5f : 1.0f;
            atomicAdd(&out[d], dt * wj * v);
        }
    }
}

extern "C" void kernel_launch(void* const* d_in, const int* in_sizes, int n_in,
                              void* d_out, int out_size, void* d_ws, size_t ws_size,
                              hipStream_t stream) {
    const float* z0  = (const float*)d_in[0];
    const float* t   = (const float*)d_in[1];
    const float* W1  = (const float*)d_in[2];
    const float* b1  = (const float*)d_in[3];
    const float* W2  = (const float*)d_in[4];
    const float* b2  = (const float*)d_in[5];
    const float* Wk1 = (const float*)d_in[6];
    const float* bk1 = (const float*)d_in[7];
    const float* Wk2 = (const float*)d_in[8];
    const float* bk2 = (const float*)d_in[9];
    float* out = (float*)d_out;

    float* ws  = (float*)d_ws;
    float* A   = ws;                          // T*T*HK     = 2,097,152 (8 MB)
    float* M   = A   + (size_t)TT*TT*HKD;     // T*HK*D     = 1,048,576
    float* F   = M   + (size_t)TT*HKD*DD;     // T*D
    float* bF  = F   + TT*DD;                 // T*D
    float* G   = bF  + TT*DD;                 // T*D
    float* P   = G   + TT*DD;                 // NCHUNK*T*D = 524,288
    float* M0  = P   + (size_t)NCHUNK*TT*DD;  // HD = 8192
    float* bF0 = M0  + HD;                    // DD

    static int use_coop = -1;   // decided on first (non-captured) call

    if (use_coop != 0) {
        void* args[] = {
            (void*)&z0, (void*)&t, (void*)&W1, (void*)&b1, (void*)&W2, (void*)&b2,
            (void*)&Wk1, (void*)&bk1, (void*)&Wk2, (void*)&bk2,
            (void*)&A, (void*)&M, (void*)&F, (void*)&bF, (void*)&G, (void*)&P,
            (void*)&M0, (void*)&bF0, (void*)&out
        };
        hipError_t e = hipLaunchCooperativeKernel((const void*)mega, dim3(NBLK),
                                                  dim3(256), args, 0, stream);
        if (e == hipSuccess) { use_coop = 1; return; }
        (void)hipGetLastError();   // clear sticky error, fall through
        use_coop = 0;
    }

    // Fallback: proven 10-launch pipeline
    k_F0M0<<<32, 256, 0, stream>>>(z0, W1, b1, W2, b2, bk2, Wk2, M0, bF0);
    k_G0<<<TT, 256, 0, stream>>>(t, Wk1, bk1, M0, bF0, G);
    for (int it = 1; it < 3; ++it) {
        int fin = (it == 2) ? 1 : 0;
        k_F<<<TT, 256, 0, stream>>>(G, z0, t, W1, b1, W2, b2, bk2, F, bF);
        k_M<<<dim3(32, 16), 256, 0, stream>>>(F, Wk2, M);
        k_G1<<<dim3(16, NCHUNK), 256, 0, stream>>>(t, Wk1, bk1, M, P, z0, out, fin);
        k_Gfin<<<TT, 256, 0, stream>>>(P, bF, t, G, out, fin);
    }
}

// Round 3
// 391.469 us; speedup vs baseline: 1.1735x; 1.1735x over previous
//
#include <hip/hip_runtime.h>

// Problem constants (from reference)
#define TT 128    // time points
#define DD 64     // state dim
#define HH 256    // f-net hidden
#define HKD 128   // kernel-net hidden
#define HD (HKD*DD)        // 8192
#define NB 512             // grid: 2 blocks/CU (64 VGPR, 16KB LDS -> guaranteed resident)

// Shared memory union — max member (g1) = 16 KB.
union __attribute__((aligned(16))) SharedU {
    struct { float red[4][64]; float ys[DD]; float hs[HH]; float fs[DD]; } f;   // MLP phases
    struct { float Bpart[2][HKD]; float Bs[HKD]; float red[4][64]; } g0;        // it0 G
    struct { float Fs[8][DD]; } m;                                              // M phase
    struct { float As[8 * 256]; float red[4][8][64]; } g1;                      // G1 phase
};

// ---------------------------------------------------------------------------
// Hand-rolled grid barrier (replaces cg::grid.sync(), which measured ~37 us).
// Arrival: one relaxed agent-scope store per block to its OWN slot (no RMW
// contention). Block 0 scans all slots (256 threads x 2), publishes go=gen.
// Fences: release (wbL2) before arrive, acquire (invL2) after go — the
// minimum for cross-XCD visibility of normal L2-cached stores.
// flags[NB] and go are memset to 0 on-stream before launch.
// ---------------------------------------------------------------------------
__device__ __forceinline__ void gbar(int* flags, int* go, int gen, int b, int tid) {
    __syncthreads();                       // all waves' stores drained (vmcnt) before fence
    if (tid == 0) {
        __builtin_amdgcn_fence(__ATOMIC_RELEASE, "agent");   // wb dirty L2 -> L3
        __hip_atomic_store(&flags[b], gen, __ATOMIC_RELAXED, __HIP_MEMORY_SCOPE_AGENT);
    }
    if (b == 0) {
        bool ok;
        do {
            int v1 = __hip_atomic_load(&flags[tid],       __ATOMIC_RELAXED, __HIP_MEMORY_SCOPE_AGENT);
            int v2 = __hip_atomic_load(&flags[tid + 256], __ATOMIC_RELAXED, __HIP_MEMORY_SCOPE_AGENT);
            ok = (v1 >= gen) && (v2 >= gen);
            if (!ok) __builtin_amdgcn_s_sleep(1);
        } while (!__syncthreads_and(ok));
        if (tid == 0)
            __hip_atomic_store(go, gen, __ATOMIC_RELAXED, __HIP_MEMORY_SCOPE_AGENT);
    } else if (tid == 0) {
        while (__hip_atomic_load(go, __ATOMIC_RELAXED, __HIP_MEMORY_SCOPE_AGENT) < gen)
            __builtin_amdgcn_s_sleep(2);   // backoff: don't hammer the L3 slice
    }
    __syncthreads();
    __builtin_amdgcn_fence(__ATOMIC_ACQUIRE, "agent");       // inv stale L1/L2
}

// f-MLP: requires sm.f.ys valid (+synced); leaves f(y) in sm.f.fs (synced).
__device__ __forceinline__ void mlp_f(SharedU& sm, int tid,
                                      const float* __restrict__ W1, const float* __restrict__ b1,
                                      const float* __restrict__ W2, const float* __restrict__ b2) {
    int part = tid >> 6, d = tid & 63;
    float acc = b1[tid];
    #pragma unroll 8
    for (int e = 0; e < DD; ++e) acc += sm.f.ys[e] * W1[e * HH + tid];
    sm.f.hs[tid] = tanhf(acc);
    __syncthreads();
    float s = 0.f;
    #pragma unroll 8
    for (int h = part * 64; h < part * 64 + 64; ++h) s += sm.f.hs[h] * W2[h * DD + d];
    sm.f.red[part][d] = s;
    __syncthreads();
    if (part == 0)
        sm.f.fs[d] = b2[d] + sm.f.red[0][d] + sm.f.red[1][d] + sm.f.red[2][d] + sm.f.red[3][d];
    __syncthreads();
}

// bF[d] = sum_e bk2[d*DD+e]*fs[e]; valid for all threads on return.
__device__ __forceinline__ float bk2dot(SharedU& sm, int tid, const float* __restrict__ bk2) {
    int part = tid >> 6, d = tid & 63;
    float s = 0.f;
    #pragma unroll
    for (int e = part * 16; e < part * 16 + 16; ++e) s += bk2[d * DD + e] * sm.f.fs[e];
    sm.f.red[part][d] = s;
    __syncthreads();
    return sm.f.red[0][d] + sm.f.red[1][d] + sm.f.red[2][d] + sm.f.red[3][d];
}

extern "C" __global__ void __launch_bounds__(256, 2)
mega(const float* __restrict__ z0, const float* __restrict__ t,
     const float* __restrict__ W1, const float* __restrict__ b1,
     const float* __restrict__ W2, const float* __restrict__ b2,
     const float* __restrict__ Wk1, const float* __restrict__ bk1,
     const float* __restrict__ Wk2, const float* __restrict__ bk2,
     float* __restrict__ A, float* __restrict__ M,
     float* __restrict__ F, float* __restrict__ bF,
     float* __restrict__ G, float* __restrict__ P,
     float* __restrict__ M0, float* __restrict__ bF0,
     int* flags, int* go, float* __restrict__ out)
{
    const int b = blockIdx.x, tid = threadIdx.x;
    const int part = tid >> 6, d = tid & 63;
    __shared__ SharedU sm;
    const float dt = t[1] - t[0];
    int gen = 0;

    // ===== P0: A[i][j][h] = w_ij * tanh(t_i*wk0 + t_j*wk1 + bk)  (iteration-invariant)
    // blocks 0..31 additionally: f0 = f(z0) -> M0 slice; block 0 -> bF0.
    if (b < 32) {
        if (tid < DD) sm.f.ys[tid] = z0[tid];
        __syncthreads();
        mlp_f(sm, tid, W1, b1, W2, b2);
        if (b == 0) {
            float v = bk2dot(sm, tid, bk2);
            if (part == 0) bF0[d] = v;
        }
        int hd = b * 256 + tid;
        const float* Wrow = Wk2 + (size_t)(hd >> 6) * (DD * DD) + (size_t)(hd & 63) * DD;
        float a = 0.f;
        #pragma unroll
        for (int e = 0; e < DD; e += 8) {
            float4 wa = *(const float4*)(Wrow + e);
            float4 wb = *(const float4*)(Wrow + e + 4);
            float4 fa = *(const float4*)&sm.f.fs[e];
            float4 fb = *(const float4*)&sm.f.fs[e + 4];
            a += fa.x*wa.x + fa.y*wa.y + fa.z*wa.z + fa.w*wa.w
               + fb.x*wb.x + fb.y*wb.y + fb.z*wb.z + fb.w*wb.w;
        }
        M0[hd] = a;
    }
    {
        // 4096 entries/block, 16/thread. i = b>>2 is block-constant.
        const int h = tid & 127;
        const float wk0 = Wk1[h], wk1v = Wk1[HKD + h], bk = bk1[h];
        const int i = b >> 2;
        const float ti = t[i];
        const int base = b * 4096;
        #pragma unroll 4
        for (int k = 0; k < 16; ++k) {
            int n = base + k * 256 + tid;
            int j = (n >> 7) & 127;
            float w = (i == 0 || j > i) ? 0.f : dt * ((j == 0 || j == i) ? 0.5f : 1.f);
            float v = 0.f;
            if (w != 0.f)   // wave-uniform (j constant within a wave)
                v = w * tanhf(ti * wk0 + t[j] * wk1v + bk);
            A[n] = v;
        }
    }
    gbar(flags, go, ++gen, b, tid);

    // ===== P1 (it0): G_i = sum_h B[i,h]*M0[h,d] + dt*i*bF0[d],  B = rowsum of A
    if (b < TT) {
        const int i = b;
        const int h = tid & 127, half = tid >> 7;
        float bsum = 0.f;
        const float* Ai = A + (size_t)i * (TT * HKD);
        for (int j = half; j <= i; j += 2) bsum += Ai[j * HKD + h];
        sm.g0.Bpart[half][h] = bsum;
        __syncthreads();
        if (tid < HKD) sm.g0.Bs[tid] = sm.g0.Bpart[0][tid] + sm.g0.Bpart[1][tid];
        __syncthreads();
        float a = 0.f;
        #pragma unroll 8
        for (int h2 = part * 32; h2 < part * 32 + 32; ++h2) a += sm.g0.Bs[h2] * M0[h2 * DD + d];
        sm.g0.red[part][d] = a;
        __syncthreads();
        if (part == 0) {
            float g = sm.g0.red[0][d] + sm.g0.red[1][d] + sm.g0.red[2][d] + sm.g0.red[3][d];
            if (i > 0) g += dt * (float)i * bF0[d];
            G[i * DD + d] = g;
        }
    }
    gbar(flags, go, ++gen, b, tid);

    // ===== it = 1, 2 =====
    for (int it = 1; it < 3; ++it) {
        const int fin = (it == 2);

        // --- F phase: blocks 0..127: y_j from prefix of G, then F[j], bF[j] ---
        if (b < TT) {
            const int j = b;
            float s = 0.f;
            if (j > 0) {
                for (int jp = part; jp <= j; jp += 4) {
                    float w = (jp == 0 || jp == j) ? 0.5f : 1.0f;
                    s += w * G[jp * DD + d];
                }
            }
            sm.f.red[part][d] = s;
            __syncthreads();
            if (part == 0)
                sm.f.ys[d] = z0[d] + dt * (sm.f.red[0][d] + sm.f.red[1][d] + sm.f.red[2][d] + sm.f.red[3][d]);
            __syncthreads();
            mlp_f(sm, tid, W1, b1, W2, b2);
            if (part == 0) F[j * DD + d] = sm.f.fs[d];
            float v = bk2dot(sm, tid, bk2);
            if (part == 0) bF[j * DD + d] = v;
        }
        gbar(flags, go, ++gen, b, tid);

        // --- M phase: 512 units, 1 per block. M[j,hd] = sum_e F[j,e]*Wk2[h, d*DD+e] ---
        {
            const int hd = (b & 31) * 256 + tid;
            const int j0 = (b >> 5) * 8;
            for (int k2 = tid; k2 < 8 * DD; k2 += 256) sm.m.Fs[k2 >> 6][k2 & 63] = F[j0 * DD + k2];
            __syncthreads();
            float acc[8] = {0.f,0.f,0.f,0.f,0.f,0.f,0.f,0.f};
            const float* Wrow = Wk2 + (size_t)(hd >> 6) * (DD * DD) + (size_t)(hd & 63) * DD;
            for (int e = 0; e < DD; e += 8) {
                float4 wa = *(const float4*)(Wrow + e);
                float4 wb = *(const float4*)(Wrow + e + 4);
                #pragma unroll
                for (int r = 0; r < 8; ++r) {
                    float4 f0 = *(const float4*)&sm.m.Fs[r][e];
                    float4 f1 = *(const float4*)&sm.m.Fs[r][e + 4];
                    acc[r] += f0.x*wa.x + f0.y*wa.y + f0.z*wa.z + f0.w*wa.w
                            + f1.x*wb.x + f1.y*wb.y + f1.z*wb.z + f1.w*wb.w;
                }
            }
            #pragma unroll
            for (int r = 0; r < 8; ++r) M[(size_t)(j0 + r) * HD + hd] = acc[r];
        }
        gbar(flags, go, ++gen, b, tid);

        // --- G1 phase: 544 (itile,c) units; blocks 0..31 take a second unit ---
        if (fin && b == 0 && tid < DD) out[tid] = z0[tid];   // seed out = z0
        for (int u = b; u < 544; u += NB) {
            int uu = u, itile = 0;
            while (uu >= 4 * (itile + 1)) { uu -= 4 * (itile + 1); ++itile; }
            const int c = uu;               // c <= 4*itile+3 by construction
            __syncthreads();                // protect As/red reuse across units
            const float* Asrc = A + ((size_t)(itile * 8) * TT + 2 * c) * HKD;
            for (int q = tid; q < 8 * 64; q += 256) {       // 8 rows x 256 floats, float4
                int r = q >> 6, c4 = q & 63;
                ((float4*)sm.g1.As)[r * 64 + c4] =
                    *(const float4*)(Asrc + (size_t)r * TT * HKD + c4 * 4);
            }
            __syncthreads();
            float acc[8] = {0.f,0.f,0.f,0.f,0.f,0.f,0.f,0.f};
            const float* Mp = M + ((size_t)c * 256) * DD + d;
            const int jl0 = part * 64;
            for (int jl = jl0; jl < jl0 + 64; jl += 8) {
                float m0 = Mp[(size_t)(jl + 0) * DD];
                float m1 = Mp[(size_t)(jl + 1) * DD];
                float m2 = Mp[(size_t)(jl + 2) * DD];
                float m3 = Mp[(size_t)(jl + 3) * DD];
                float m4 = Mp[(size_t)(jl + 4) * DD];
                float m5 = Mp[(size_t)(jl + 5) * DD];
                float m6 = Mp[(size_t)(jl + 6) * DD];
                float m7 = Mp[(size_t)(jl + 7) * DD];
                #pragma unroll
                for (int r = 0; r < 8; ++r) {
                    float4 a0 = *(const float4*)&sm.g1.As[r * 256 + jl];
                    float4 a1 = *(const float4*)&sm.g1.As[r * 256 + jl + 4];
                    acc[r] += a0.x*m0 + a0.y*m1 + a0.z*m2 + a0.w*m3
                            + a1.x*m4 + a1.y*m5 + a1.z*m6 + a1.w*m7;
                }
            }
            #pragma unroll
            for (int r = 0; r < 8; ++r) sm.g1.red[part][r][d] = acc[r];
            __syncthreads();
            if (part == 0) {
                #pragma unroll
                for (int r = 0; r < 8; ++r) {
                    float v = sm.g1.red[0][r][d] + sm.g1.red[1][r][d]
                            + sm.g1.red[2][r][d] + sm.g1.red[3][r][d];
                    P[(size_t)c * (TT * DD) + (itile * 8 + r) * DD + d] = v;
                }
            }
        }
        gbar(flags, go, ++gen, b, tid);

        // --- Gfin phase: blocks 0..127: G[j] = sum_c P[c,j,:] + dt*trap(bF) ---
        if (b < TT) {
            const int j = b;
            float a = 0.f;
            const int cmax = j >> 1;
            for (int c = part; c <= cmax; c += 4) a += P[(size_t)c * (TT * DD) + j * DD + d];
            if (j > 0) {
                float s2 = 0.f;
                for (int jp = part; jp <= j; jp += 4) {
                    float w = (jp == 0 || jp == j) ? 0.5f : 1.0f;
                    s2 += w * bF[jp * DD + d];
                }
                a += dt * s2;
            }
            sm.f.red[part][d] = a;
            __syncthreads();
            if (part == 0) {
                float v = sm.f.red[0][d] + sm.f.red[1][d] + sm.f.red[2][d] + sm.f.red[3][d];
                G[j * DD + d] = v;
                if (fin) {
                    float wj = (j == 0 || j == TT - 1) ? 0.5f : 1.0f;
                    atomicAdd(&out[d], dt * wj * v);
                }
            }
        }
        if (it == 1) gbar(flags, go, ++gen, b, tid);
    }
}

extern "C" void kernel_launch(void* const* d_in, const int* in_sizes, int n_in,
                              void* d_out, int out_size, void* d_ws, size_t ws_size,
                              hipStream_t stream) {
    const float* z0  = (const float*)d_in[0];
    const float* t   = (const float*)d_in[1];
    const float* W1  = (const float*)d_in[2];
    const float* b1  = (const float*)d_in[3];
    const float* W2  = (const float*)d_in[4];
    const float* b2  = (const float*)d_in[5];
    const float* Wk1 = (const float*)d_in[6];
    const float* bk1 = (const float*)d_in[7];
    const float* Wk2 = (const float*)d_in[8];
    const float* bk2 = (const float*)d_in[9];
    float* out = (float*)d_out;

    float* ws  = (float*)d_ws;
    float* A   = ws;                          // T*T*HK     = 2,097,152 (8 MB)
    float* M   = A   + (size_t)TT*TT*HKD;     // T*HK*D     = 1,048,576
    float* F   = M   + (size_t)TT*HKD*DD;     // T*D
    float* bF  = F   + TT*DD;                 // T*D
    float* G   = bF  + TT*DD;                 // T*D
    float* P   = G   + TT*DD;                 // 64*T*D     = 524,288
    float* M0  = P   + (size_t)64*TT*DD;      // HD = 8192
    float* bF0 = M0  + HD;                    // DD
    int*   flags = (int*)(bF0 + DD);          // NB slots
    int*   go    = flags + NB;                // 1 slot

    // Zero barrier state (captured into the graph -> re-zeroed every replay).
    hipMemsetAsync(flags, 0, (NB + 1) * sizeof(int), stream);

    void* args[] = {
        (void*)&z0, (void*)&t, (void*)&W1, (void*)&b1, (void*)&W2, (void*)&b2,
        (void*)&Wk1, (void*)&bk1, (void*)&Wk2, (void*)&bk2,
        (void*)&A, (void*)&M, (void*)&F, (void*)&bF, (void*)&G, (void*)&P,
        (void*)&M0, (void*)&bF0, (void*)&flags, (void*)&go, (void*)&out
    };
    // Normal launch: 512 blocks at 2 blocks/CU (64 VGPR, 16KB LDS) are fully
    // co-resident on 256 CUs; the hand-rolled barrier needs no coop launch.
    hipLaunchKernel((const void*)mega, dim3(NB), dim3(256), args, 0, stream);
}

// Round 4
// 347.073 us; speedup vs baseline: 1.3236x; 1.1279x over previous
//
#include <hip/hip_runtime.h>

// Problem constants (from reference)
#define TT 128    // time points
#define DD 64     // state dim
#define HH 256    // f-net hidden
#define HKD 128   // kernel-net hidden
#define HD (HKD*DD)   // 8192

// ---------------------------------------------------------------------------
// k_init — one launch doing everything that has no upstream dependency:
//   blocks 128..639 : A[i][j][h] = w_ij * tanh(t_i*wk0 + t_j*wk1 + bk)
//                     (iteration-invariant, consumed by both k_G1a calls)
//   blocks 0..127   : it0 G row i (y==z0 degenerate):
//                     G0_i[d] = sum_h B[i,h]*M0[h,d] + dt*i*bF0[d]
//                     with f0, B-row, M0-column and bF0 computed inline
//                     (replaces the old F0M0+G0 kernel pair).
// ---------------------------------------------------------------------------
__global__ void __launch_bounds__(256)
k_init(const float* __restrict__ z0, const float* __restrict__ t,
       const float* __restrict__ W1, const float* __restrict__ b1,
       const float* __restrict__ W2, const float* __restrict__ b2,
       const float* __restrict__ Wk1, const float* __restrict__ bk1,
       const float* __restrict__ Wk2, const float* __restrict__ bk2,
       float* __restrict__ A, float* __restrict__ G0)
{
    const int b = blockIdx.x, tid = threadIdx.x;
    const float dt = t[1] - t[0];

    if (b >= 128) {
        // ---- A precompute: 4096 entries/block, i = (b-128)>>2 is block-constant
        const int ab = b - 128;
        const int h = tid & 127;
        const float wk0 = Wk1[h], wk1v = Wk1[HKD + h], bk = bk1[h];
        const int i = ab >> 2;
        const float ti = t[i];
        const int base = ab * 4096;
        #pragma unroll 4
        for (int k = 0; k < 16; ++k) {
            int n = base + k * 256 + tid;
            int j = (n >> 7) & 127;
            float w = (i == 0 || j > i) ? 0.f : dt * ((j == 0 || j == i) ? 0.5f : 1.f);
            float v = 0.f;
            if (w != 0.f)   // wave-uniform (j constant within a wave)
                v = w * tanhf(ti * wk0 + t[j] * wk1v + bk);
            A[n] = v;
        }
        return;
    }

    // ---- it0 G row i
    const int i = b;
    const int part = tid >> 6, d = tid & 63;
    __shared__ float red[4][64];
    __shared__ float ys[DD];
    __shared__ float hs[HH];
    __shared__ __attribute__((aligned(16))) float fs[DD];
    __shared__ float Bpart[2][HKD];
    __shared__ float Bs[HKD];

    if (i == 0) {                    // zero-length integral: G[0] = 0
        if (part == 0) G0[d] = 0.f;
        return;                      // uniform exit, no barrier after
    }

    // f0 = f(z0)
    if (tid < DD) ys[tid] = z0[tid];
    __syncthreads();
    float acc = b1[tid];
    #pragma unroll 8
    for (int e = 0; e < DD; ++e) acc += ys[e] * W1[e * HH + tid];
    hs[tid] = tanhf(acc);
    __syncthreads();
    {
        float s = 0.f;
        #pragma unroll 8
        for (int h = part * 64; h < part * 64 + 64; ++h) s += hs[h] * W2[h * DD + d];
        red[part][d] = s;
    }
    __syncthreads();
    if (part == 0)
        fs[d] = b2[d] + red[0][d] + red[1][d] + red[2][d] + red[3][d];
    __syncthreads();

    // B-row i (on-the-fly tanh, proven r9 k_G0 logic)
    {
        const int h = tid & 127, half = tid >> 7;
        const float wk0 = Wk1[h], wk1v = Wk1[HKD + h], bk = bk1[h];
        const float ti = t[i];
        float bsum = 0.f;
        for (int j = half; j <= i; j += 2) {
            float w = dt * ((j == 0 || j == i) ? 0.5f : 1.0f);
            bsum += w * tanhf(ti * wk0 + t[j] * wk1v + bk);
        }
        Bpart[half][h] = bsum;
    }
    __syncthreads();
    if (tid < HKD) Bs[tid] = Bpart[0][tid] + Bpart[1][tid];
    __syncthreads();

    // G0_i[d] = sum_h Bs[h] * M0[h,d],  M0[h,d] = sum_e Wk2[h*4096 + d*64 + e]*fs[e]
    float a = 0.f;
    for (int h2 = part * 32; h2 < part * 32 + 32; ++h2) {
        const float* Wrow = Wk2 + (size_t)h2 * 4096 + (size_t)d * DD;
        float m = 0.f;
        #pragma unroll
        for (int e = 0; e < DD; e += 8) {
            float4 wa = *(const float4*)(Wrow + e);
            float4 wb = *(const float4*)(Wrow + e + 4);
            float4 fa = *(const float4*)&fs[e];
            float4 fb = *(const float4*)&fs[e + 4];
            m += fa.x*wa.x + fa.y*wa.y + fa.z*wa.z + fa.w*wa.w
               + fb.x*wb.x + fb.y*wb.y + fb.z*wb.z + fb.w*wb.w;
        }
        a += Bs[h2] * m;
    }
    red[part][d] = a;
    __syncthreads();
    if (part == 0) {
        // bF0[d] = bk2[d,:] . f0  (16 float4 loads, inline)
        const float* br = bk2 + (size_t)d * DD;
        float bf = 0.f;
        #pragma unroll
        for (int e = 0; e < DD; e += 8) {
            float4 wa = *(const float4*)(br + e);
            float4 wb = *(const float4*)(br + e + 4);
            float4 fa = *(const float4*)&fs[e];
            float4 fb = *(const float4*)&fs[e + 4];
            bf += fa.x*wa.x + fa.y*wa.y + fa.z*wa.z + fa.w*wa.w
                + fb.x*wb.x + fb.y*wb.y + fb.z*wb.z + fb.w*wb.w;
        }
        float g = red[0][d] + red[1][d] + red[2][d] + red[3][d];
        G0[i * DD + d] = g + dt * (float)i * bf;
    }
}

// ---------------------------------------------------------------------------
// k_FM — fused F+M. 512 blocks, 4 per row j (j = b>>2, quarter q = b&3):
//   all: y_j = z0 + dt*trap(Gin[0..j]); f_j = MLP(y_j)
//   q==0: bF[j] = bk2 . f_j ; zero Gz[j] (the G buffer the next k_G1a fills)
//   each: M[j, q*2048 .. q*2048+2047] = Wk2-rows . f_j
// ---------------------------------------------------------------------------
__global__ void __launch_bounds__(256)
k_FM(const float* __restrict__ Gin, float* __restrict__ Gz,
     const float* __restrict__ z0, const float* __restrict__ t,
     const float* __restrict__ W1, const float* __restrict__ b1,
     const float* __restrict__ W2, const float* __restrict__ b2,
     const float* __restrict__ bk2, const float* __restrict__ Wk2,
     float* __restrict__ M, float* __restrict__ bF)
{
    const int b = blockIdx.x, tid = threadIdx.x;
    const int j = b >> 2, q = b & 3;
    const int part = tid >> 6, d = tid & 63;
    __shared__ float red[4][64];
    __shared__ float ys[DD];
    __shared__ float hs[HH];
    __shared__ __attribute__((aligned(16))) float fs[DD];
    const float dt = t[1] - t[0];

    // y_j from prefix of Gin
    {
        float s = 0.f;
        if (j > 0) {
            for (int jp = part; jp <= j; jp += 4) {
                float w = (jp == 0 || jp == j) ? 0.5f : 1.0f;
                s += w * Gin[jp * DD + d];
            }
        }
        red[part][d] = s;
        __syncthreads();
        if (part == 0)
            ys[d] = z0[d] + dt * (red[0][d] + red[1][d] + red[2][d] + red[3][d]);
    }
    __syncthreads();

    // f_j = tanh(y@W1+b1)@W2+b2
    float acc = b1[tid];
    #pragma unroll 8
    for (int e = 0; e < DD; ++e) acc += ys[e] * W1[e * HH + tid];
    hs[tid] = tanhf(acc);
    __syncthreads();
    {
        float s = 0.f;
        #pragma unroll 8
        for (int h = part * 64; h < part * 64 + 64; ++h) s += hs[h] * W2[h * DD + d];
        red[part][d] = s;
    }
    __syncthreads();
    if (part == 0)
        fs[d] = b2[d] + red[0][d] + red[1][d] + red[2][d] + red[3][d];
    __syncthreads();

    if (q == 0) {
        float s = 0.f;
        #pragma unroll
        for (int e = part * 16; e < part * 16 + 16; ++e) s += bk2[d * DD + e] * fs[e];
        red[part][d] = s;
        __syncthreads();
        if (part == 0) {
            bF[j * DD + d] = red[0][d] + red[1][d] + red[2][d] + red[3][d];
            Gz[j * DD + d] = 0.f;   // pre-zero for k_G1a's atomics
        }
    }

    // M quarter: hd in [q*2048, q*2048+2048)
    const int hb = q * 2048;
    #pragma unroll
    for (int k = 0; k < 8; ++k) {
        int hd = hb + k * 256 + tid;
        const float* Wrow = Wk2 + (size_t)hd * DD;   // (hd>>6)*4096+(hd&63)*64 == hd*64
        float a = 0.f;
        #pragma unroll
        for (int e = 0; e < DD; e += 8) {
            float4 wa = *(const float4*)(Wrow + e);
            float4 wb = *(const float4*)(Wrow + e + 4);
            float4 fa = *(const float4*)&fs[e];
            float4 fb = *(const float4*)&fs[e + 4];
            a += fa.x*wa.x + fa.y*wa.y + fa.z*wa.z + fa.w*wa.w
               + fb.x*wb.x + fb.y*wb.y + fb.z*wb.z + fb.w*wb.w;
        }
        M[(size_t)j * HD + hd] = a;
    }
}

// ---------------------------------------------------------------------------
// k_G1a — fused G1+Gfin. grid (16 itiles, 64 chunks), active iff c<=4*itile+3.
// Computes the chunk partial and atomicAdds it directly into Gout (pre-zeroed
// by k_FM). c==0 block of each itile also adds the dt*trap(bF) term.
// A-weights are zero for j>i, so inactive-row contributions are exact zeros.
// ---------------------------------------------------------------------------
__global__ void __launch_bounds__(256)
k_G1a(const float* __restrict__ A, const float* __restrict__ M,
      const float* __restrict__ bF, const float* __restrict__ t,
      float* __restrict__ Gout)
{
    const int itile = blockIdx.x, c = blockIdx.y;
    if (c > 4 * itile + 3) return;
    __shared__ __attribute__((aligned(16))) float As[8 * 256];
    __shared__ float red[4][8][64];
    const int tid = threadIdx.x, part = tid >> 6, d = tid & 63;
    const float dt = t[1] - t[0];

    const float* Asrc = A + ((size_t)(itile * 8) * TT + 2 * c) * HKD;
    for (int qq = tid; qq < 8 * 64; qq += 256) {      // 8 rows x 256 floats, float4
        int r = qq >> 6, c4 = qq & 63;
        ((float4*)As)[r * 64 + c4] = *(const float4*)(Asrc + (size_t)r * TT * HKD + c4 * 4);
    }
    __syncthreads();

    float acc[8] = {0.f,0.f,0.f,0.f,0.f,0.f,0.f,0.f};
    const float* Mp = M + ((size_t)c * 256) * DD + d;
    const int jl0 = part * 64;
    for (int jl = jl0; jl < jl0 + 64; jl += 8) {
        float m0 = Mp[(size_t)(jl + 0) * DD];
        float m1 = Mp[(size_t)(jl + 1) * DD];
        float m2 = Mp[(size_t)(jl + 2) * DD];
        float m3 = Mp[(size_t)(jl + 3) * DD];
        float m4 = Mp[(size_t)(jl + 4) * DD];
        float m5 = Mp[(size_t)(jl + 5) * DD];
        float m6 = Mp[(size_t)(jl + 6) * DD];
        float m7 = Mp[(size_t)(jl + 7) * DD];
        #pragma unroll
        for (int r = 0; r < 8; ++r) {
            float4 a0 = *(const float4*)&As[r * 256 + jl];
            float4 a1 = *(const float4*)&As[r * 256 + jl + 4];
            acc[r] += a0.x*m0 + a0.y*m1 + a0.z*m2 + a0.w*m3
                    + a1.x*m4 + a1.y*m5 + a1.z*m6 + a1.w*m7;
        }
    }
    #pragma unroll
    for (int r = 0; r < 8; ++r) red[part][r][d] = acc[r];
    __syncthreads();
    if (part == 0) {
        #pragma unroll
        for (int r = 0; r < 8; ++r) {
            float v = red[0][r][d] + red[1][r][d] + red[2][r][d] + red[3][r][d];
            atomicAdd(&Gout[(itile * 8 + r) * DD + d], v);
        }
        // bF trapezoid term, once per itile
        if (c == 0) {
            const int i0 = itile * 8;
            float run = 0.5f * bF[d];    // jp = 0 half-weight
            int p = 0;                   // bF[1..p] fully accumulated into run
            for (int r = 0; r < 8; ++r) {
                int i = i0 + r;
                if (i == 0) continue;    // G[0] has no integral term
                while (p < i - 1) { ++p; run += bF[p * DD + d]; }
                float term = dt * (run + 0.5f * bF[i * DD + d]);
                atomicAdd(&Gout[i * DD + d], term);
            }
        }
    }
}

// ---------------------------------------------------------------------------
// k_out — out[d] = z0[d] + dt * trap_j(G[j,d]). One block.
// ---------------------------------------------------------------------------
__global__ void __launch_bounds__(256)
k_out(const float* __restrict__ G, const float* __restrict__ z0,
      const float* __restrict__ t, float* __restrict__ out)
{
    const int tid = threadIdx.x, part = tid >> 6, d = tid & 63;
    __shared__ float red[4][64];
    const float dt = t[1] - t[0];
    float s = 0.f;
    for (int j = part; j < TT; j += 4) {
        float w = (j == 0 || j == TT - 1) ? 0.5f : 1.0f;
        s += w * G[j * DD + d];
    }
    red[part][d] = s;
    __syncthreads();
    if (part == 0)
        out[d] = z0[d] + dt * (red[0][d] + red[1][d] + red[2][d] + red[3][d]);
}

extern "C" void kernel_launch(void* const* d_in, const int* in_sizes, int n_in,
                              void* d_out, int out_size, void* d_ws, size_t ws_size,
                              hipStream_t stream) {
    const float* z0  = (const float*)d_in[0];
    const float* t   = (const float*)d_in[1];
    const float* W1  = (const float*)d_in[2];
    const float* b1  = (const float*)d_in[3];
    const float* W2  = (const float*)d_in[4];
    const float* b2  = (const float*)d_in[5];
    const float* Wk1 = (const float*)d_in[6];
    const float* bk1 = (const float*)d_in[7];
    const float* Wk2 = (const float*)d_in[8];
    const float* bk2 = (const float*)d_in[9];
    float* out = (float*)d_out;

    float* ws = (float*)d_ws;
    float* A  = ws;                        // T*T*HK  = 2,097,152 floats (8 MB)
    float* M  = A  + (size_t)TT*TT*HKD;    // T*HK*D  = 1,048,576 (4 MB)
    float* Ga = M  + (size_t)TT*HKD*DD;    // T*D  (it0 G, then it2 G)
    float* Gb = Ga + TT*DD;                // T*D  (it1 G)
    float* bF = Gb + TT*DD;                // T*D

    // 6 launches (was 10). Stream order provides cross-XCD coherence between
    // dependent kernels; in-kernel grid barriers measured ~34us each (r2/r3).
    k_init<<<640, 256, 0, stream>>>(z0, t, W1, b1, W2, b2, Wk1, bk1, Wk2, bk2, A, Ga);
    // it1: read Ga, zero+fill Gb
    k_FM<<<512, 256, 0, stream>>>(Ga, Gb, z0, t, W1, b1, W2, b2, bk2, Wk2, M, bF);
    k_G1a<<<dim3(16, 64), 256, 0, stream>>>(A, M, bF, t, Gb);
    // it2: read Gb, zero+fill Ga
    k_FM<<<512, 256, 0, stream>>>(Gb, Ga, z0, t, W1, b1, W2, b2, bk2, Wk2, M, bF);
    k_G1a<<<dim3(16, 64), 256, 0, stream>>>(A, M, bF, t, Ga);
    k_out<<<1, 256, 0, stream>>>(Ga, z0, t, out);
}